// Round 20
// baseline (157.991 us; speedup 1.0000x reference)
//
#include <hip/hip_runtime.h>

typedef unsigned short ushort;
typedef unsigned char uchar;
typedef unsigned long long u64;
typedef __attribute__((ext_vector_type(8))) short short8;   // 8 bf16 in 4 VGPRs
typedef __attribute__((ext_vector_type(4))) float f32x4;
typedef __attribute__((ext_vector_type(4))) unsigned int uint4v;

#define B_ 4
#define S_ 2048
#define E_ 512
#define H_ 8
#define D_ 64
#define LDT 40   // padded LDS row stride (bf16) for GEMM tiles
#define LDF 68   // flash LDS row stride: 2-way bank aliasing only (free)

__device__ inline ushort f2bf(float f) {
  union { float f; unsigned int u; } v; v.f = f;
  unsigned int u = v.u;
  unsigned int r = u + 0x7FFFu + ((u >> 16) & 1u);   // RNE
  return (ushort)(r >> 16);
}

// packed f32x2 -> bf16x2 (gfx950 v_cvt_pk_bf16_f32)
__device__ inline unsigned int cvt_pk_bf16(float a, float b) {
  unsigned int r;
  asm("v_cvt_pk_bf16_f32 %0, %1, %2" : "=v"(r) : "v"(a), "v"(b));
  return r;
}

// hazard-safe 2^x: compiler-visible intrinsic (TRANS hazards handled by backend)
__device__ inline float exp2_fast(float x) {
#if defined(__has_builtin)
#if __has_builtin(__builtin_amdgcn_exp2f)
  return __builtin_amdgcn_exp2f(x);
#else
  return __expf(x * 0.69314718056f);
#endif
#else
  return __expf(x * 0.69314718056f);
#endif
}

// zero out P lanes whose paired A2 value has the attn-discard sign bit set
__device__ inline short8 mask_keep(short8 p, short8 a2) {
  union U { short8 s; uint4v u; } P, A;
  P.s = p; A.s = a2;
#pragma unroll
  for (int i = 0; i < 4; ++i) {
    unsigned int t = A.u[i] & 0x80008000u;
    unsigned int dm = (t >> 15) * 0xFFFFu;   // 0xFFFF per discarded u16
    P.u[i] &= ~dm;
  }
  return P.s;
}

// 16-lane (DPP row) sum reduction on the VALU pipe (used once, post-loop)
__device__ inline float dpp_sum16(float v) {
  union { float f; int i; } s, t;
  s.f = v;
  t.i = __builtin_amdgcn_update_dpp(0, s.i, 0x128, 0xf, 0xf, false); s.f += t.f;
  t.i = __builtin_amdgcn_update_dpp(0, s.i, 0x124, 0xf, 0xf, false); s.f += t.f;
  t.i = __builtin_amdgcn_update_dpp(0, s.i, 0x122, 0xf, 0xf, false); s.f += t.f;
  t.i = __builtin_amdgcn_update_dpp(0, s.i, 0x121, 0xf, 0xf, false); s.f += t.f;
  return s.f;
}

// ---------------- convert weights: W[h][e][d]->wt[p][n][e] (y<3) and fcw->fcwbf (y==3) ----------------
__global__ __launch_bounds__(256) void convert_weights_kernel(
    const float* __restrict__ Wq, const float* __restrict__ Wk, const float* __restrict__ Wv,
    const float* __restrict__ fcw,
    ushort* __restrict__ wt, ushort* __restrict__ fcwbf) {
  const int p = blockIdx.y;
  const int n = blockIdx.x;
  if (p == 3) {
    const float* src = fcw + (size_t)n * E_;
    ushort* o = fcwbf + (size_t)n * E_;
    for (int e = threadIdx.x; e < E_; e += 256) o[e] = f2bf(src[e]);
    return;
  }
  const float* W = (p == 0) ? Wq : (p == 1) ? Wk : Wv;
  const int h = n >> 6, d = n & 63;
  ushort* o = wt + ((size_t)p * E_ + n) * E_;
  for (int e = threadIdx.x; e < E_; e += 256)
    o[e] = f2bf(W[((size_t)h * E_ + e) * D_ + d]);
}

// ---------------- MFMA projection GEMM: dbuf LDS (1 barrier/K-step) + reg prefetch + XCD swizzle ----------------
// q-head pre-scaled by 0.125*log2(e) so flash's softmax is a bare 2^x
__global__ __launch_bounds__(256) void proj_gemm_kernel(
    const float* __restrict__ qx, const float* __restrict__ kx, const float* __restrict__ vx,
    const ushort* __restrict__ wt,
    const float* __restrict__ bq, const float* __restrict__ bk, const float* __restrict__ bv,
    ushort* __restrict__ qkv) {
  const int phys = blockIdx.x;
  const int logical = (phys & 7) * 96 + (phys >> 3);
  const int p = logical >> 8;
  const int rem = logical & 255;
  const int m0 = (rem >> 2) * 128, n0 = (rem & 3) * 128;

  const float* A   = (p == 0) ? qx : (p == 1) ? kx : vx;
  const ushort* Bt = wt + (size_t)p * (E_ * E_);
  const float* bias = (p == 0) ? bq : (p == 1) ? bk : bv;
  const float osc = (p == 0) ? 0.125f * 1.44269504f : 1.0f;
  ushort* out = qkv + (size_t)p * (B_ * H_ * S_ * D_);

  const int tid = threadIdx.x;
  const int w = tid >> 6, lane = tid & 63;
  const int g = lane >> 4, c = lane & 15;
  const int wr = w >> 1, wc = w & 1;

  __shared__ ushort As[2][128][LDT], Bs[2][128][LDT];

  f32x4 acc[4][4];
#pragma unroll
  for (int i = 0; i < 4; ++i)
#pragma unroll
    for (int j = 0; j < 4; ++j) acc[i][j] = (f32x4){0, 0, 0, 0};

  const int srow = tid >> 2, sc8 = (tid & 3) * 8;
  float4 pa0[2], pa1[2];
  short8 pb[2];

#pragma unroll
  for (int it = 0; it < 2; ++it) {
    const float* ap = &A[(size_t)(m0 + srow + 64 * it) * E_ + sc8];
    float4 a0 = *(const float4*)ap;
    float4 a1 = *(const float4*)(ap + 4);
    unsigned int r0 = cvt_pk_bf16(a0.x, a0.y), r1 = cvt_pk_bf16(a0.z, a0.w);
    unsigned int r2 = cvt_pk_bf16(a1.x, a1.y), r3 = cvt_pk_bf16(a1.z, a1.w);
    short8 av;
    av[0] = (short)(ushort)r0; av[1] = (short)(ushort)(r0 >> 16);
    av[2] = (short)(ushort)r1; av[3] = (short)(ushort)(r1 >> 16);
    av[4] = (short)(ushort)r2; av[5] = (short)(ushort)(r2 >> 16);
    av[6] = (short)(ushort)r3; av[7] = (short)(ushort)(r3 >> 16);
    *(short8*)&As[0][srow + 64 * it][sc8] = av;
    *(short8*)&Bs[0][srow + 64 * it][sc8] = *(const short8*)&Bt[(size_t)(n0 + srow + 64 * it) * E_ + sc8];
  }
#pragma unroll
  for (int it = 0; it < 2; ++it) {
    const float* ap = &A[(size_t)(m0 + srow + 64 * it) * E_ + 32 + sc8];
    pa0[it] = *(const float4*)ap;
    pa1[it] = *(const float4*)(ap + 4);
    pb[it] = *(const short8*)&Bt[(size_t)(n0 + srow + 64 * it) * E_ + 32 + sc8];
  }
  __syncthreads();

  for (int ks = 0; ks < 16; ++ks) {
    const int cur = ks & 1;
    short8 af[4], bfr[4];
#pragma unroll
    for (int i = 0; i < 4; ++i) af[i] = *(const short8*)&As[cur][wr * 64 + i * 16 + c][8 * g];
#pragma unroll
    for (int j = 0; j < 4; ++j) bfr[j] = *(const short8*)&Bs[cur][wc * 64 + j * 16 + c][8 * g];
#pragma unroll
    for (int i = 0; i < 4; ++i)
#pragma unroll
      for (int j = 0; j < 4; ++j)
        acc[i][j] = __builtin_amdgcn_mfma_f32_16x16x32_bf16(af[i], bfr[j], acc[i][j], 0, 0, 0);

    if (ks + 1 < 16) {
#pragma unroll
      for (int it = 0; it < 2; ++it) {
        unsigned int r0 = cvt_pk_bf16(pa0[it].x, pa0[it].y), r1 = cvt_pk_bf16(pa0[it].z, pa0[it].w);
        unsigned int r2 = cvt_pk_bf16(pa1[it].x, pa1[it].y), r3 = cvt_pk_bf16(pa1[it].z, pa1[it].w);
        short8 av;
        av[0] = (short)(ushort)r0; av[1] = (short)(ushort)(r0 >> 16);
        av[2] = (short)(ushort)r1; av[3] = (short)(ushort)(r1 >> 16);
        av[4] = (short)(ushort)r2; av[5] = (short)(ushort)(r2 >> 16);
        av[6] = (short)(ushort)r3; av[7] = (short)(ushort)(r3 >> 16);
        *(short8*)&As[cur ^ 1][srow + 64 * it][sc8] = av;
        *(short8*)&Bs[cur ^ 1][srow + 64 * it][sc8] = pb[it];
      }
      if (ks + 2 < 16) {
        const int kk = (ks + 2) * 32;
#pragma unroll
        for (int it = 0; it < 2; ++it) {
          const float* ap = &A[(size_t)(m0 + srow + 64 * it) * E_ + kk + sc8];
          pa0[it] = *(const float4*)ap;
          pa1[it] = *(const float4*)(ap + 4);
          pb[it] = *(const short8*)&Bt[(size_t)(n0 + srow + 64 * it) * E_ + kk + sc8];
        }
      }
    }
    __syncthreads();
  }

#pragma unroll
  for (int i = 0; i < 4; ++i)
#pragma unroll
    for (int jj = 0; jj < 4; ++jj) {
      int grow = m0 + wr * 64 + i * 16 + 4 * g + jj;
      int b = grow >> 11, s = grow & 2047;
#pragma unroll
      for (int j = 0; j < 4; ++j) {
        int col = n0 + wc * 64 + j * 16 + c;
        int h = col >> 6, d = col & 63;
        out[(((size_t)(b * H_ + h)) * S_ + s) * D_ + d] = f2bf((acc[i][j][jj] + bias[col]) * osc);
      }
    }
}

// ---------------- m2dist STANDALONE: zero LDS (8 blocks/CU), 4 q-rows/block, batched ILP ----------------
// dtype detect: per-wave __any over the first 1 KB — every wave independently reaches the
// same verdict (int32: all high-bytes zero; bool: P(64 random words all zero-high) ~ 8^-64).
__global__ __launch_bounds__(256) void m2dist_kernel(
    const float* __restrict__ cq, const float* __restrict__ ck,
    const void* __restrict__ am_raw, const void* __restrict__ alm_raw,
    ushort* __restrict__ m2d) {
  const int tid = threadIdx.x;
  unsigned int probe = ((const unsigned int*)am_raw)[tid];   // L2-hot broadcast
  const bool isInt = !__any((probe & 0xFFFFFF00u) != 0);

  const int mid = blockIdx.x;           // 0..2047
  const int b = mid >> 9;               // 512 blocks per batch
  const int q0 = (mid & 511) * 4;       // 4 consecutive q-rows
  const int k0 = tid * 8;
  const size_t rb0 = ((size_t)b * S_ + q0) * S_ + k0;

  // k-coords: shared by all 4 rows
  float c24[24];
  {
    const float* ckp = ck + ((size_t)b * S_ + k0) * 3;
#pragma unroll
    for (int t = 0; t < 6; ++t) {
      float4 cv = *(const float4*)(ckp + 4 * t);
      c24[4 * t] = cv.x; c24[4 * t + 1] = cv.y; c24[4 * t + 2] = cv.z; c24[4 * t + 3] = cv.w;
    }
  }
  // q-coords for the 4 rows: 12 consecutive floats
  float qc[12];
  {
    const float* cqp = cq + ((size_t)b * S_ + q0) * 3;
#pragma unroll
    for (int t = 0; t < 3; ++t) {
      float4 cv = *(const float4*)(cqp + 4 * t);
      qc[4 * t] = cv.x; qc[4 * t + 1] = cv.y; qc[4 * t + 2] = cv.z; qc[4 * t + 3] = cv.w;
    }
  }
  // masks for all 4 rows, packed to one byte per k
  u64 ab[4], lb[4];
  if (isInt) {
#pragma unroll
    for (int r = 0; r < 4; ++r) {
      const size_t rowbase = rb0 + (size_t)r * S_;
      int4 A0 = *(const int4*)&((const int*)am_raw)[rowbase];
      int4 A1 = *(const int4*)&((const int*)am_raw)[rowbase + 4];
      int4 L0 = *(const int4*)&((const int*)alm_raw)[rowbase];
      int4 L1 = *(const int4*)&((const int*)alm_raw)[rowbase + 4];
      u64 av = 0, lv = 0;
      av |= (u64)(A0.x ? 1 : 0);       lv |= (u64)(L0.x ? 1 : 0);
      av |= (u64)(A0.y ? 1 : 0) << 8;  lv |= (u64)(L0.y ? 1 : 0) << 8;
      av |= (u64)(A0.z ? 1 : 0) << 16; lv |= (u64)(L0.z ? 1 : 0) << 16;
      av |= (u64)(A0.w ? 1 : 0) << 24; lv |= (u64)(L0.w ? 1 : 0) << 24;
      av |= (u64)(A1.x ? 1 : 0) << 32; lv |= (u64)(L1.x ? 1 : 0) << 32;
      av |= (u64)(A1.y ? 1 : 0) << 40; lv |= (u64)(L1.y ? 1 : 0) << 40;
      av |= (u64)(A1.z ? 1 : 0) << 48; lv |= (u64)(L1.z ? 1 : 0) << 48;
      av |= (u64)(A1.w ? 1 : 0) << 56; lv |= (u64)(L1.w ? 1 : 0) << 56;
      ab[r] = av; lb[r] = lv;
    }
  } else {
#pragma unroll
    for (int r = 0; r < 4; ++r) {
      const size_t rowbase = rb0 + (size_t)r * S_;
      ab[r] = *(const u64*)&((const uchar*)am_raw)[rowbase];
      lb[r] = *(const u64*)&((const uchar*)alm_raw)[rowbase];
    }
  }

#pragma unroll
  for (int r = 0; r < 4; ++r) {
    const float qx2 = qc[3 * r], qy2 = qc[3 * r + 1], qz2 = qc[3 * r + 2];
    float dist[8];
#pragma unroll
    for (int j = 0; j < 8; ++j) {
      const float dx = qx2 - c24[3 * j], dy = qy2 - c24[3 * j + 1], dz = qz2 - c24[3 * j + 2];
      dist[j] = sqrtf(dx * dx + dy * dy + dz * dz);
    }
    short8 md;
#pragma unroll
    for (int jp = 0; jp < 4; ++jp) {
      const int a0 = (int)((ab[r] >> (16 * jp)) & 0xFF);
      const int a1 = (int)((ab[r] >> (16 * jp + 8)) & 0xFF);
      const int l0 = (int)((lb[r] >> (16 * jp)) & 0xFF);
      const int l1 = (int)((lb[r] >> (16 * jp + 8)) & 0xFF);
      unsigned int rr = cvt_pk_bf16(dist[2 * jp], dist[2 * jp + 1]);
      ushort v0 = (!a0 && !l0) ? (ushort)rr         : (ushort)0;
      ushort v1 = (!a1 && !l1) ? (ushort)(rr >> 16) : (ushort)0;
      if (a0) v0 |= 0x8000u;
      if (a1) v1 |= 0x8000u;
      md[2 * jp] = (short)v0; md[2 * jp + 1] = (short)v1;
    }
    *(short8*)&m2d[rb0 + (size_t)r * S_] = md;
  }
}

// ---------------- transpose V: vh [bh][s][d] -> vtg [bh][d][s] ----------------
__global__ __launch_bounds__(256) void transpose_v_kernel(
    const ushort* __restrict__ vh, ushort* __restrict__ vtg) {
  const int bh = blockIdx.y, s0 = blockIdx.x * 64;
  __shared__ ushort tile[64][70];
  const int tid = threadIdx.x;
#pragma unroll
  for (int it = 0; it < 2; ++it) {
    int chunk = tid + 256 * it;
    int r = chunk >> 3, c8 = chunk & 7;
    *(short8*)&tile[r][c8 * 8] = *(const short8*)&vh[((size_t)bh * S_ + s0 + r) * D_ + c8 * 8];
  }
  __syncthreads();
#pragma unroll
  for (int it = 0; it < 2; ++it) {
    int chunk = tid + 256 * it;
    int d = chunk >> 3, s8 = chunk & 7;
    short8 o;
#pragma unroll
    for (int j = 0; j < 8; ++j) o[j] = (short)tile[s8 * 8 + j][d];
    *(short8*)&vtg[((size_t)bh * D_ + d) * S_ + s0 + s8 * 8] = o;
  }
}

// ---------------- flash attention (r13-proven): QBLK=128, 8 waves, dbuf K/V, 1 barrier/tile ----------------
__global__ __launch_bounds__(512) void flash_kernel(
    const ushort* __restrict__ qh, const ushort* __restrict__ kh, const ushort* __restrict__ vtg,
    const ushort* __restrict__ m2d,
    const float* __restrict__ bscale, const float* __restrict__ rmean,
    ushort* __restrict__ attb) {
  const int flat = blockIdx.x;
  const int h = flat >> 6;
  const int grp = flat & 63;
  const int b = grp >> 4;
  const int qb = (grp & 15) * 128;
  const int bh = b * 8 + h;
  const int tid = threadIdx.x;
  const int w = tid >> 6, lane = tid & 63;
  const int g = lane >> 4, c = lane & 15;

  __shared__ ushort Kt[2][64][LDF];
  __shared__ ushort Vt[2][64][LDF];
  __shared__ ushort Pl[8][16][LDF];

  const size_t bhS = (size_t)bh * S_;
  const int qrow_a = qb + 16 * w + c;
  const short8 aq0 = *(const short8*)(qh + (bhS + qrow_a) * D_ + 8 * g);
  const short8 aq1 = *(const short8*)(qh + (bhS + qrow_a) * D_ + 8 * g + 32);

  const int skr = tid >> 3, sc8 = (tid & 7) * 8;
  const ushort* pk0 = kh + (bhS + skr) * D_ + sc8;
  const ushort* pv0 = vtg + ((size_t)bh * D_ + skr) * S_ + sc8;
  const ushort* pm0 = m2d + ((size_t)b * S_ + qrow_a) * S_ + 8 * g;
  const ushort* pm1 = pm0 + 32;

  f32x4 acc1[4], acc2[4];
#pragma unroll
  for (int t = 0; t < 4; ++t) { acc1[t] = (f32x4){0,0,0,0}; acc2[t] = (f32x4){0,0,0,0}; }
  float l[4] = {0, 0, 0, 0};

  {
    short8 k0 = *(const short8*)pk0;  pk0 += 64 * D_;
    short8 v0 = *(const short8*)pv0;  pv0 += 64;
    *(short8*)&Kt[0][skr][sc8] = k0;
    *(short8*)&Vt[0][skr][sc8] = v0;
  }
  short8 a2n0 = *(const short8*)pm0; pm0 += 64;
  short8 a2n1 = *(const short8*)pm1; pm1 += 64;
  short8 skn = *(const short8*)pk0;  pk0 += 64 * D_;
  short8 svn = *(const short8*)pv0;  pv0 += 64;
  __syncthreads();

  for (int kb = 0; kb < S_; kb += 64) {
    const int cur = (kb >> 6) & 1;
    short8 a2c0 = a2n0, a2c1 = a2n1;
    a2n0 = *(const short8*)pm0; pm0 += 64;
    a2n1 = *(const short8*)pm1; pm1 += 64;

    f32x4 sf[4];
    __builtin_amdgcn_s_setprio(1);
#pragma unroll
    for (int t = 0; t < 4; ++t) {
      short8 b0 = *(const short8*)&Kt[cur][16 * t + c][8 * g];
      short8 b1 = *(const short8*)&Kt[cur][16 * t + c][8 * g + 32];
      f32x4 z = (f32x4){0, 0, 0, 0};
      z = __builtin_amdgcn_mfma_f32_16x16x32_bf16(aq0, b0, z, 0, 0, 0);
      z = __builtin_amdgcn_mfma_f32_16x16x32_bf16(aq1, b1, z, 0, 0, 0);
      sf[t] = z;
    }
    __builtin_amdgcn_s_setprio(0);

#pragma unroll
    for (int t = 0; t < 4; ++t)
#pragma unroll
      for (int jp = 0; jp < 2; ++jp) {
        float p0 = exp2_fast(sf[t][2 * jp]);
        float p1 = exp2_fast(sf[t][2 * jp + 1]);
        l[2 * jp] += p0; l[2 * jp + 1] += p1;
        unsigned int r = cvt_pk_bf16(p0, p1);
        Pl[w][4 * g + 2 * jp][16 * t + c]     = (ushort)r;
        Pl[w][4 * g + 2 * jp + 1][16 * t + c] = (ushort)(r >> 16);
      }

    asm volatile("s_waitcnt lgkmcnt(0)" ::: "memory");
    __builtin_amdgcn_sched_barrier(0);

    short8 pa0 = *(const short8*)&Pl[w][c][8 * g];
    short8 pa1 = *(const short8*)&Pl[w][c][8 * g + 32];
    pa0 = mask_keep(pa0, a2c0);
    pa1 = mask_keep(pa1, a2c1);
    __builtin_amdgcn_s_setprio(1);
#pragma unroll
    for (int t2 = 0; t2 < 4; ++t2) {
      short8 v0 = *(const short8*)&Vt[cur][16 * t2 + c][8 * g];
      short8 v1 = *(const short8*)&Vt[cur][16 * t2 + c][8 * g + 32];
      acc1[t2] = __builtin_amdgcn_mfma_f32_16x16x32_bf16(pa0, v0, acc1[t2], 0, 0, 0);
      acc1[t2] = __builtin_amdgcn_mfma_f32_16x16x32_bf16(pa1, v1, acc1[t2], 0, 0, 0);
      acc2[t2] = __builtin_amdgcn_mfma_f32_16x16x32_bf16(a2c0, v0, acc2[t2], 0, 0, 0);
      acc2[t2] = __builtin_amdgcn_mfma_f32_16x16x32_bf16(a2c1, v1, acc2[t2], 0, 0, 0);
    }
    __builtin_amdgcn_s_setprio(0);

    if (kb + 64 < S_) {
      *(short8*)&Kt[cur ^ 1][skr][sc8] = skn;
      *(short8*)&Vt[cur ^ 1][skr][sc8] = svn;
      skn = *(const short8*)pk0;  pk0 += 64 * D_;
      svn = *(const short8*)pv0;  pv0 += 64;
    }
    __syncthreads();
  }

  float linv[4];
#pragma unroll
  for (int j = 0; j < 4; ++j) linv[j] = 1.0f / dpp_sum16(l[j]);
  const float scale = bscale[h] / rmean[h];
#pragma unroll
  for (int t2 = 0; t2 < 4; ++t2)
#pragma unroll
    for (int j = 0; j < 4; ++j) {
      int qr = qb + 16 * w + 4 * g + j;
      int d = 16 * t2 + c;
      attb[(((size_t)b * S_ + qr) * H_ + h) * D_ + d] =
          f2bf(acc1[t2][j] * linv[j] - scale * acc2[t2][j]);
    }
}

// ---------------- MFMA output GEMM: dbuf LDS (1 barrier/K-step) + reg prefetch + XCD swizzle ----------------
__global__ __launch_bounds__(256) void final_gemm_kernel(
    const ushort* __restrict__ attb, const ushort* __restrict__ fcwbf,
    const float* __restrict__ fcb, float* __restrict__ out) {
  const int phys = blockIdx.x;
  const int logical = (phys & 7) * 32 + (phys >> 3);
  const int m0 = (logical >> 2) * 128, n0 = (logical & 3) * 128;
  const int tid = threadIdx.x;
  const int w = tid >> 6, lane = tid & 63;
  const int g = lane >> 4, c = lane & 15;
  const int wr = w >> 1, wc = w & 1;

  __shared__ ushort As[2][128][LDT], Bs[2][128][LDT];

  f32x4 acc[4][4];
#pragma unroll
  for (int i = 0; i < 4; ++i)
#pragma unroll
    for (int j = 0; j < 4; ++j) acc[i][j] = (f32x4){0, 0, 0, 0};

  const int srow = tid >> 2, sc8 = (tid & 3) * 8;
  short8 pa[2], pb[2];

#pragma unroll
  for (int it = 0; it < 2; ++it) {
    *(short8*)&As[0][srow + 64 * it][sc8] = *(const short8*)&attb[(size_t)(m0 + srow + 64 * it) * E_ + sc8];
    *(short8*)&Bs[0][srow + 64 * it][sc8] = *(const short8*)&fcwbf[(size_t)(n0 + srow + 64 * it) * E_ + sc8];
  }
#pragma unroll
  for (int it = 0; it < 2; ++it) {
    pa[it] = *(const short8*)&attb[(size_t)(m0 + srow + 64 * it) * E_ + 32 + sc8];
    pb[it] = *(const short8*)&fcwbf[(size_t)(n0 + srow + 64 * it) * E_ + 32 + sc8];
  }
  __syncthreads();

  for (int ks = 0; ks < 16; ++ks) {
    const int cur = ks & 1;
    short8 af[4], bfr[4];
#pragma unroll
    for (int i = 0; i < 4; ++i) af[i] = *(const short8*)&As[cur][wr * 64 + i * 16 + c][8 * g];
#pragma unroll
    for (int j = 0; j < 4; ++j) bfr[j] = *(const short8*)&Bs[cur][wc * 64 + j * 16 + c][8 * g];
#pragma unroll
    for (int i = 0; i < 4; ++i)
#pragma unroll
      for (int j = 0; j < 4; ++j)
        acc[i][j] = __builtin_amdgcn_mfma_f32_16x16x32_bf16(af[i], bfr[j], acc[i][j], 0, 0, 0);

    if (ks + 1 < 16) {
#pragma unroll
      for (int it = 0; it < 2; ++it) {
        *(short8*)&As[cur ^ 1][srow + 64 * it][sc8] = pa[it];
        *(short8*)&Bs[cur ^ 1][srow + 64 * it][sc8] = pb[it];
      }
      if (ks + 2 < 16) {
        const int kk = (ks + 2) * 32;
#pragma unroll
        for (int it = 0; it < 2; ++it) {
          pa[it] = *(const short8*)&attb[(size_t)(m0 + srow + 64 * it) * E_ + kk + sc8];
          pb[it] = *(const short8*)&fcwbf[(size_t)(n0 + srow + 64 * it) * E_ + kk + sc8];
        }
      }
    }
    __syncthreads();
  }

#pragma unroll
  for (int i = 0; i < 4; ++i)
#pragma unroll
    for (int jj = 0; jj < 4; ++jj) {
      int grow = m0 + wr * 64 + i * 16 + 4 * g + jj;
#pragma unroll
      for (int j = 0; j < 4; ++j) {
        int col = n0 + wc * 64 + j * 16 + c;
        out[(size_t)grow * E_ + col] = acc[i][j][jj] + fcb[col];
      }
    }
}

extern "C" void kernel_launch(void* const* d_in, const int* in_sizes, int n_in,
                              void* d_out, int out_size, void* d_ws, size_t ws_size,
                              hipStream_t stream) {
  const float* q   = (const float*)d_in[0];
  const float* k   = (const float*)d_in[1];
  const float* v   = (const float*)d_in[2];
  const float* cq  = (const float*)d_in[3];
  const float* ck  = (const float*)d_in[4];
  const void*  am  = d_in[5];
  const void*  alm = d_in[6];
  const float* Wq  = (const float*)d_in[7];
  const float* bq  = (const float*)d_in[8];
  const float* Wk  = (const float*)d_in[9];
  const float* bk  = (const float*)d_in[10];
  const float* Wv  = (const float*)d_in[11];
  const float* bv  = (const float*)d_in[12];
  const float* bsc = (const float*)d_in[13];
  const float* rm  = (const float*)d_in[14];
  const float* fcw = (const float*)d_in[15];
  const float* fcb = (const float*)d_in[16];
  float* out = (float*)d_out;

  char* ws = (char*)d_ws;
  ushort* attb = (ushort*)(ws);                              // 8 MiB (bf16)
  ushort* vtg  = (ushort*)(ws + 16ull * 1024 * 1024);        // 8 MiB
  ushort* qkv  = (ushort*)(ws + 24ull * 1024 * 1024);        // 24 MiB (qh,kh,vh)
  ushort* m2d  = (ushort*)(ws + 48ull * 1024 * 1024);        // 32 MiB (sign bit = attn-discard)
  ushort* wt   = (ushort*)(ws + 80ull * 1024 * 1024);        // 1.5 MiB
  ushort* fcwbf= (ushort*)(ws + 80ull * 1024 * 1024 + 1536 * 1024); // 0.5 MiB

  ushort* qh = qkv;
  ushort* kh = qkv + (size_t)(B_ * H_ * S_ * D_);
  ushort* vh = qkv + 2 * (size_t)(B_ * H_ * S_ * D_);

  convert_weights_kernel<<<dim3(512, 4), 256, 0, stream>>>(Wq, Wk, Wv, fcw, wt, fcwbf);
  proj_gemm_kernel<<<768, 256, 0, stream>>>(q, k, v, wt, bq, bk, bv, qkv);
  m2dist_kernel<<<2048, 256, 0, stream>>>(cq, ck, am, alm, m2d);
  transpose_v_kernel<<<dim3(S_ / 64, B_ * H_), 256, 0, stream>>>(vh, vtg);
  flash_kernel<<<512, 512, 0, stream>>>(qh, kh, vtg, m2d, bsc, rm, attb);
  final_gemm_kernel<<<256, 256, 0, stream>>>(attb, fcwbf, fcb, out);
}

// Round 21
// 152.719 us; speedup vs baseline: 1.0345x; 1.0345x over previous
//
#include <hip/hip_runtime.h>

typedef unsigned short ushort;
typedef unsigned char uchar;
typedef unsigned long long u64;
typedef __attribute__((ext_vector_type(8))) short short8;   // 8 bf16 in 4 VGPRs
typedef __attribute__((ext_vector_type(4))) float f32x4;
typedef __attribute__((ext_vector_type(4))) unsigned int uint4v;

#define B_ 4
#define S_ 2048
#define E_ 512
#define H_ 8
#define D_ 64
#define LDT 40   // padded LDS row stride (bf16) for GEMM tiles
#define LDF 68   // flash LDS row stride: 2-way bank aliasing only (free)

__device__ inline ushort f2bf(float f) {
  union { float f; unsigned int u; } v; v.f = f;
  unsigned int u = v.u;
  unsigned int r = u + 0x7FFFu + ((u >> 16) & 1u);   // RNE
  return (ushort)(r >> 16);
}

// packed f32x2 -> bf16x2 (gfx950 v_cvt_pk_bf16_f32)
__device__ inline unsigned int cvt_pk_bf16(float a, float b) {
  unsigned int r;
  asm("v_cvt_pk_bf16_f32 %0, %1, %2" : "=v"(r) : "v"(a), "v"(b));
  return r;
}

// hazard-safe 2^x: compiler-visible intrinsic (TRANS hazards handled by backend)
__device__ inline float exp2_fast(float x) {
#if defined(__has_builtin)
#if __has_builtin(__builtin_amdgcn_exp2f)
  return __builtin_amdgcn_exp2f(x);
#else
  return __expf(x * 0.69314718056f);
#endif
#else
  return __expf(x * 0.69314718056f);
#endif
}

// zero out P lanes whose paired A2 value has the attn-discard sign bit set
__device__ inline short8 mask_keep(short8 p, short8 a2) {
  union U { short8 s; uint4v u; } P, A;
  P.s = p; A.s = a2;
#pragma unroll
  for (int i = 0; i < 4; ++i) {
    unsigned int t = A.u[i] & 0x80008000u;
    unsigned int dm = (t >> 15) * 0xFFFFu;   // 0xFFFF per discarded u16
    P.u[i] &= ~dm;
  }
  return P.s;
}

// 16-lane (DPP row) sum reduction on the VALU pipe (used once, post-loop)
__device__ inline float dpp_sum16(float v) {
  union { float f; int i; } s, t;
  s.f = v;
  t.i = __builtin_amdgcn_update_dpp(0, s.i, 0x128, 0xf, 0xf, false); s.f += t.f;
  t.i = __builtin_amdgcn_update_dpp(0, s.i, 0x124, 0xf, 0xf, false); s.f += t.f;
  t.i = __builtin_amdgcn_update_dpp(0, s.i, 0x122, 0xf, 0xf, false); s.f += t.f;
  t.i = __builtin_amdgcn_update_dpp(0, s.i, 0x121, 0xf, 0xf, false); s.f += t.f;
  return s.f;
}

// ---------------- convert weights: W[h][e][d]->wt[p][n][e] (y<3) and fcw->fcwbf (y==3) ----------------
__global__ __launch_bounds__(256) void convert_weights_kernel(
    const float* __restrict__ Wq, const float* __restrict__ Wk, const float* __restrict__ Wv,
    const float* __restrict__ fcw,
    ushort* __restrict__ wt, ushort* __restrict__ fcwbf) {
  const int p = blockIdx.y;
  const int n = blockIdx.x;
  if (p == 3) {
    const float* src = fcw + (size_t)n * E_;
    ushort* o = fcwbf + (size_t)n * E_;
    for (int e = threadIdx.x; e < E_; e += 256) o[e] = f2bf(src[e]);
    return;
  }
  const float* W = (p == 0) ? Wq : (p == 1) ? Wk : Wv;
  const int h = n >> 6, d = n & 63;
  ushort* o = wt + ((size_t)p * E_ + n) * E_;
  for (int e = threadIdx.x; e < E_; e += 256)
    o[e] = f2bf(W[((size_t)h * E_ + e) * D_ + d]);
}

// ---------------- PHASE 1 (fused): proj GEMM SINGLE-BUF (20.5 KB LDS -> 7 blocks/CU for BOTH sides)
// blocks 0..767: proj (r11-proven single-buffer + reg prefetch, chunked XCD swizzle)
// blocks 768..2815: m2dist, zero-LDS pure-wave ballot detect, 4 q-rows/block, batched ILP
__global__ __launch_bounds__(256) void phase1_kernel(
    const float* __restrict__ qx, const float* __restrict__ kx, const float* __restrict__ vx,
    const ushort* __restrict__ wt,
    const float* __restrict__ bq, const float* __restrict__ bk, const float* __restrict__ bv,
    ushort* __restrict__ qkv,
    const float* __restrict__ cq, const float* __restrict__ ck,
    const void* __restrict__ am_raw, const void* __restrict__ alm_raw,
    ushort* __restrict__ m2d) {
  __shared__ ushort As[128][LDT], Bs[128][LDT];   // 20,480 B total
  const int bid = blockIdx.x;
  const int tid = threadIdx.x;

  if (bid < 768) {
    // ================= proj GEMM: single-buffered LDS + register prefetch =================
    const int logical = (bid & 7) * 96 + (bid >> 3);
    const int p = logical >> 8;
    const int rem = logical & 255;
    const int m0 = (rem >> 2) * 128, n0 = (rem & 3) * 128;

    const float* A   = (p == 0) ? qx : (p == 1) ? kx : vx;
    const ushort* Bt = wt + (size_t)p * (E_ * E_);
    const float* bias = (p == 0) ? bq : (p == 1) ? bk : bv;
    const float osc = (p == 0) ? 0.125f * 1.44269504f : 1.0f;
    ushort* out = qkv + (size_t)p * (B_ * H_ * S_ * D_);

    const int w = tid >> 6, lane = tid & 63;
    const int g = lane >> 4, c = lane & 15;
    const int wr = w >> 1, wc = w & 1;

    f32x4 acc[4][4];
#pragma unroll
    for (int i = 0; i < 4; ++i)
#pragma unroll
      for (int j = 0; j < 4; ++j) acc[i][j] = (f32x4){0, 0, 0, 0};

    const int srow = tid >> 2, sc8 = (tid & 3) * 8;
    float4 pa0[2], pa1[2];
    short8 pb[2];
#pragma unroll
    for (int it = 0; it < 2; ++it) {
      const float* ap = &A[(size_t)(m0 + srow + 64 * it) * E_ + sc8];
      pa0[it] = *(const float4*)ap;
      pa1[it] = *(const float4*)(ap + 4);
      pb[it] = *(const short8*)&Bt[(size_t)(n0 + srow + 64 * it) * E_ + sc8];
    }

    for (int kk = 0; kk < E_; kk += 32) {
      __syncthreads();
#pragma unroll
      for (int it = 0; it < 2; ++it) {
        unsigned int r0 = cvt_pk_bf16(pa0[it].x, pa0[it].y), r1 = cvt_pk_bf16(pa0[it].z, pa0[it].w);
        unsigned int r2 = cvt_pk_bf16(pa1[it].x, pa1[it].y), r3 = cvt_pk_bf16(pa1[it].z, pa1[it].w);
        short8 av;
        av[0] = (short)(ushort)r0; av[1] = (short)(ushort)(r0 >> 16);
        av[2] = (short)(ushort)r1; av[3] = (short)(ushort)(r1 >> 16);
        av[4] = (short)(ushort)r2; av[5] = (short)(ushort)(r2 >> 16);
        av[6] = (short)(ushort)r3; av[7] = (short)(ushort)(r3 >> 16);
        *(short8*)&As[srow + 64 * it][sc8] = av;
        *(short8*)&Bs[srow + 64 * it][sc8] = pb[it];
      }
      __syncthreads();
      if (kk + 32 < E_) {
#pragma unroll
        for (int it = 0; it < 2; ++it) {
          const float* ap = &A[(size_t)(m0 + srow + 64 * it) * E_ + kk + 32 + sc8];
          pa0[it] = *(const float4*)ap;
          pa1[it] = *(const float4*)(ap + 4);
          pb[it] = *(const short8*)&Bt[(size_t)(n0 + srow + 64 * it) * E_ + kk + 32 + sc8];
        }
      }
      short8 af[4], bfr[4];
#pragma unroll
      for (int i = 0; i < 4; ++i) af[i] = *(const short8*)&As[wr * 64 + i * 16 + c][8 * g];
#pragma unroll
      for (int j = 0; j < 4; ++j) bfr[j] = *(const short8*)&Bs[wc * 64 + j * 16 + c][8 * g];
#pragma unroll
      for (int i = 0; i < 4; ++i)
#pragma unroll
        for (int j = 0; j < 4; ++j)
          acc[i][j] = __builtin_amdgcn_mfma_f32_16x16x32_bf16(af[i], bfr[j], acc[i][j], 0, 0, 0);
    }

#pragma unroll
    for (int i = 0; i < 4; ++i)
#pragma unroll
      for (int jj = 0; jj < 4; ++jj) {
        int grow = m0 + wr * 64 + i * 16 + 4 * g + jj;
        int b = grow >> 11, s = grow & 2047;
#pragma unroll
        for (int j = 0; j < 4; ++j) {
          int col = n0 + wc * 64 + j * 16 + c;
          int h = col >> 6, d = col & 63;
          out[(((size_t)(b * H_ + h)) * S_ + s) * D_ + d] = f2bf((acc[i][j][jj] + bias[col]) * osc);
        }
      }
    return;
  }

  // ================= m2dist: zero-LDS, 4 q-rows/block, batched ILP =================
  unsigned int probe = ((const unsigned int*)am_raw)[tid];   // L2-hot broadcast
  const bool isInt = !__any((probe & 0xFFFFFF00u) != 0);     // per-wave verdict, globally consistent

  const int mid = bid - 768;            // 0..2047
  const int b = mid >> 9;               // 512 blocks per batch
  const int q0 = (mid & 511) * 4;       // 4 consecutive q-rows
  const int k0 = tid * 8;
  const size_t rb0 = ((size_t)b * S_ + q0) * S_ + k0;

  float c24[24];
  {
    const float* ckp = ck + ((size_t)b * S_ + k0) * 3;
#pragma unroll
    for (int t = 0; t < 6; ++t) {
      float4 cv = *(const float4*)(ckp + 4 * t);
      c24[4 * t] = cv.x; c24[4 * t + 1] = cv.y; c24[4 * t + 2] = cv.z; c24[4 * t + 3] = cv.w;
    }
  }
  float qc[12];
  {
    const float* cqp = cq + ((size_t)b * S_ + q0) * 3;
#pragma unroll
    for (int t = 0; t < 3; ++t) {
      float4 cv = *(const float4*)(cqp + 4 * t);
      qc[4 * t] = cv.x; qc[4 * t + 1] = cv.y; qc[4 * t + 2] = cv.z; qc[4 * t + 3] = cv.w;
    }
  }
  u64 ab[4], lb[4];
  if (isInt) {
#pragma unroll
    for (int r = 0; r < 4; ++r) {
      const size_t rowbase = rb0 + (size_t)r * S_;
      int4 A0 = *(const int4*)&((const int*)am_raw)[rowbase];
      int4 A1 = *(const int4*)&((const int*)am_raw)[rowbase + 4];
      int4 L0 = *(const int4*)&((const int*)alm_raw)[rowbase];
      int4 L1 = *(const int4*)&((const int*)alm_raw)[rowbase + 4];
      u64 av = 0, lv = 0;
      av |= (u64)(A0.x ? 1 : 0);       lv |= (u64)(L0.x ? 1 : 0);
      av |= (u64)(A0.y ? 1 : 0) << 8;  lv |= (u64)(L0.y ? 1 : 0) << 8;
      av |= (u64)(A0.z ? 1 : 0) << 16; lv |= (u64)(L0.z ? 1 : 0) << 16;
      av |= (u64)(A0.w ? 1 : 0) << 24; lv |= (u64)(L0.w ? 1 : 0) << 24;
      av |= (u64)(A1.x ? 1 : 0) << 32; lv |= (u64)(L1.x ? 1 : 0) << 32;
      av |= (u64)(A1.y ? 1 : 0) << 40; lv |= (u64)(L1.y ? 1 : 0) << 40;
      av |= (u64)(A1.z ? 1 : 0) << 48; lv |= (u64)(L1.z ? 1 : 0) << 48;
      av |= (u64)(A1.w ? 1 : 0) << 56; lv |= (u64)(L1.w ? 1 : 0) << 56;
      ab[r] = av; lb[r] = lv;
    }
  } else {
#pragma unroll
    for (int r = 0; r < 4; ++r) {
      const size_t rowbase = rb0 + (size_t)r * S_;
      ab[r] = *(const u64*)&((const uchar*)am_raw)[rowbase];
      lb[r] = *(const u64*)&((const uchar*)alm_raw)[rowbase];
    }
  }

#pragma unroll
  for (int r = 0; r < 4; ++r) {
    const float qx2 = qc[3 * r], qy2 = qc[3 * r + 1], qz2 = qc[3 * r + 2];
    float dist[8];
#pragma unroll
    for (int j = 0; j < 8; ++j) {
      const float dx = qx2 - c24[3 * j], dy = qy2 - c24[3 * j + 1], dz = qz2 - c24[3 * j + 2];
      dist[j] = sqrtf(dx * dx + dy * dy + dz * dz);
    }
    short8 md;
#pragma unroll
    for (int jp = 0; jp < 4; ++jp) {
      const int a0 = (int)((ab[r] >> (16 * jp)) & 0xFF);
      const int a1 = (int)((ab[r] >> (16 * jp + 8)) & 0xFF);
      const int l0 = (int)((lb[r] >> (16 * jp)) & 0xFF);
      const int l1 = (int)((lb[r] >> (16 * jp + 8)) & 0xFF);
      unsigned int rr = cvt_pk_bf16(dist[2 * jp], dist[2 * jp + 1]);
      ushort v0 = (!a0 && !l0) ? (ushort)rr         : (ushort)0;
      ushort v1 = (!a1 && !l1) ? (ushort)(rr >> 16) : (ushort)0;
      if (a0) v0 |= 0x8000u;
      if (a1) v1 |= 0x8000u;
      md[2 * jp] = (short)v0; md[2 * jp + 1] = (short)v1;
    }
    *(short8*)&m2d[rb0 + (size_t)r * S_] = md;
  }
}

// ---------------- transpose V: vh [bh][s][d] -> vtg [bh][d][s] ----------------
__global__ __launch_bounds__(256) void transpose_v_kernel(
    const ushort* __restrict__ vh, ushort* __restrict__ vtg) {
  const int bh = blockIdx.y, s0 = blockIdx.x * 64;
  __shared__ ushort tile[64][70];
  const int tid = threadIdx.x;
#pragma unroll
  for (int it = 0; it < 2; ++it) {
    int chunk = tid + 256 * it;
    int r = chunk >> 3, c8 = chunk & 7;
    *(short8*)&tile[r][c8 * 8] = *(const short8*)&vh[((size_t)bh * S_ + s0 + r) * D_ + c8 * 8];
  }
  __syncthreads();
#pragma unroll
  for (int it = 0; it < 2; ++it) {
    int chunk = tid + 256 * it;
    int d = chunk >> 3, s8 = chunk & 7;
    short8 o;
#pragma unroll
    for (int j = 0; j < 8; ++j) o[j] = (short)tile[s8 * 8 + j][d];
    *(short8*)&vtg[((size_t)bh * D_ + d) * S_ + s0 + s8 * 8] = o;
  }
}

// ---------------- flash attention (r13-proven): QBLK=128, 8 waves, dbuf K/V, 1 barrier/tile ----------------
__global__ __launch_bounds__(512) void flash_kernel(
    const ushort* __restrict__ qh, const ushort* __restrict__ kh, const ushort* __restrict__ vtg,
    const ushort* __restrict__ m2d,
    const float* __restrict__ bscale, const float* __restrict__ rmean,
    ushort* __restrict__ attb) {
  const int flat = blockIdx.x;
  const int h = flat >> 6;
  const int grp = flat & 63;
  const int b = grp >> 4;
  const int qb = (grp & 15) * 128;
  const int bh = b * 8 + h;
  const int tid = threadIdx.x;
  const int w = tid >> 6, lane = tid & 63;
  const int g = lane >> 4, c = lane & 15;

  __shared__ ushort Kt[2][64][LDF];
  __shared__ ushort Vt[2][64][LDF];
  __shared__ ushort Pl[8][16][LDF];

  const size_t bhS = (size_t)bh * S_;
  const int qrow_a = qb + 16 * w + c;
  const short8 aq0 = *(const short8*)(qh + (bhS + qrow_a) * D_ + 8 * g);
  const short8 aq1 = *(const short8*)(qh + (bhS + qrow_a) * D_ + 8 * g + 32);

  const int skr = tid >> 3, sc8 = (tid & 7) * 8;
  const ushort* pk0 = kh + (bhS + skr) * D_ + sc8;
  const ushort* pv0 = vtg + ((size_t)bh * D_ + skr) * S_ + sc8;
  const ushort* pm0 = m2d + ((size_t)b * S_ + qrow_a) * S_ + 8 * g;
  const ushort* pm1 = pm0 + 32;

  f32x4 acc1[4], acc2[4];
#pragma unroll
  for (int t = 0; t < 4; ++t) { acc1[t] = (f32x4){0,0,0,0}; acc2[t] = (f32x4){0,0,0,0}; }
  float l[4] = {0, 0, 0, 0};

  {
    short8 k0 = *(const short8*)pk0;  pk0 += 64 * D_;
    short8 v0 = *(const short8*)pv0;  pv0 += 64;
    *(short8*)&Kt[0][skr][sc8] = k0;
    *(short8*)&Vt[0][skr][sc8] = v0;
  }
  short8 a2n0 = *(const short8*)pm0; pm0 += 64;
  short8 a2n1 = *(const short8*)pm1; pm1 += 64;
  short8 skn = *(const short8*)pk0;  pk0 += 64 * D_;
  short8 svn = *(const short8*)pv0;  pv0 += 64;
  __syncthreads();

  for (int kb = 0; kb < S_; kb += 64) {
    const int cur = (kb >> 6) & 1;
    short8 a2c0 = a2n0, a2c1 = a2n1;
    a2n0 = *(const short8*)pm0; pm0 += 64;
    a2n1 = *(const short8*)pm1; pm1 += 64;

    f32x4 sf[4];
    __builtin_amdgcn_s_setprio(1);
#pragma unroll
    for (int t = 0; t < 4; ++t) {
      short8 b0 = *(const short8*)&Kt[cur][16 * t + c][8 * g];
      short8 b1 = *(const short8*)&Kt[cur][16 * t + c][8 * g + 32];
      f32x4 z = (f32x4){0, 0, 0, 0};
      z = __builtin_amdgcn_mfma_f32_16x16x32_bf16(aq0, b0, z, 0, 0, 0);
      z = __builtin_amdgcn_mfma_f32_16x16x32_bf16(aq1, b1, z, 0, 0, 0);
      sf[t] = z;
    }
    __builtin_amdgcn_s_setprio(0);

#pragma unroll
    for (int t = 0; t < 4; ++t)
#pragma unroll
      for (int jp = 0; jp < 2; ++jp) {
        float p0 = exp2_fast(sf[t][2 * jp]);
        float p1 = exp2_fast(sf[t][2 * jp + 1]);
        l[2 * jp] += p0; l[2 * jp + 1] += p1;
        unsigned int r = cvt_pk_bf16(p0, p1);
        Pl[w][4 * g + 2 * jp][16 * t + c]     = (ushort)r;
        Pl[w][4 * g + 2 * jp + 1][16 * t + c] = (ushort)(r >> 16);
      }

    asm volatile("s_waitcnt lgkmcnt(0)" ::: "memory");
    __builtin_amdgcn_sched_barrier(0);

    short8 pa0 = *(const short8*)&Pl[w][c][8 * g];
    short8 pa1 = *(const short8*)&Pl[w][c][8 * g + 32];
    pa0 = mask_keep(pa0, a2c0);
    pa1 = mask_keep(pa1, a2c1);
    __builtin_amdgcn_s_setprio(1);
#pragma unroll
    for (int t2 = 0; t2 < 4; ++t2) {
      short8 v0 = *(const short8*)&Vt[cur][16 * t2 + c][8 * g];
      short8 v1 = *(const short8*)&Vt[cur][16 * t2 + c][8 * g + 32];
      acc1[t2] = __builtin_amdgcn_mfma_f32_16x16x32_bf16(pa0, v0, acc1[t2], 0, 0, 0);
      acc1[t2] = __builtin_amdgcn_mfma_f32_16x16x32_bf16(pa1, v1, acc1[t2], 0, 0, 0);
      acc2[t2] = __builtin_amdgcn_mfma_f32_16x16x32_bf16(a2c0, v0, acc2[t2], 0, 0, 0);
      acc2[t2] = __builtin_amdgcn_mfma_f32_16x16x32_bf16(a2c1, v1, acc2[t2], 0, 0, 0);
    }
    __builtin_amdgcn_s_setprio(0);

    if (kb + 64 < S_) {
      *(short8*)&Kt[cur ^ 1][skr][sc8] = skn;
      *(short8*)&Vt[cur ^ 1][skr][sc8] = svn;
      skn = *(const short8*)pk0;  pk0 += 64 * D_;
      svn = *(const short8*)pv0;  pv0 += 64;
    }
    __syncthreads();
  }

  float linv[4];
#pragma unroll
  for (int j = 0; j < 4; ++j) linv[j] = 1.0f / dpp_sum16(l[j]);
  const float scale = bscale[h] / rmean[h];
#pragma unroll
  for (int t2 = 0; t2 < 4; ++t2)
#pragma unroll
    for (int j = 0; j < 4; ++j) {
      int qr = qb + 16 * w + 4 * g + j;
      int d = 16 * t2 + c;
      attb[(((size_t)b * S_ + qr) * H_ + h) * D_ + d] =
          f2bf(acc1[t2][j] * linv[j] - scale * acc2[t2][j]);
    }
}

// ---------------- MFMA output GEMM: dbuf LDS (1 barrier/K-step) + reg prefetch + XCD swizzle ----------------
__global__ __launch_bounds__(256) void final_gemm_kernel(
    const ushort* __restrict__ attb, const ushort* __restrict__ fcwbf,
    const float* __restrict__ fcb, float* __restrict__ out) {
  const int phys = blockIdx.x;
  const int logical = (phys & 7) * 32 + (phys >> 3);
  const int m0 = (logical >> 2) * 128, n0 = (logical & 3) * 128;
  const int tid = threadIdx.x;
  const int w = tid >> 6, lane = tid & 63;
  const int g = lane >> 4, c = lane & 15;
  const int wr = w >> 1, wc = w & 1;

  __shared__ ushort As[2][128][LDT], Bs[2][128][LDT];

  f32x4 acc[4][4];
#pragma unroll
  for (int i = 0; i < 4; ++i)
#pragma unroll
    for (int j = 0; j < 4; ++j) acc[i][j] = (f32x4){0, 0, 0, 0};

  const int srow = tid >> 2, sc8 = (tid & 3) * 8;
  short8 pa[2], pb[2];

#pragma unroll
  for (int it = 0; it < 2; ++it) {
    *(short8*)&As[0][srow + 64 * it][sc8] = *(const short8*)&attb[(size_t)(m0 + srow + 64 * it) * E_ + sc8];
    *(short8*)&Bs[0][srow + 64 * it][sc8] = *(const short8*)&fcwbf[(size_t)(n0 + srow + 64 * it) * E_ + sc8];
  }
#pragma unroll
  for (int it = 0; it < 2; ++it) {
    pa[it] = *(const short8*)&attb[(size_t)(m0 + srow + 64 * it) * E_ + 32 + sc8];
    pb[it] = *(const short8*)&fcwbf[(size_t)(n0 + srow + 64 * it) * E_ + 32 + sc8];
  }
  __syncthreads();

  for (int ks = 0; ks < 16; ++ks) {
    const int cur = ks & 1;
    short8 af[4], bfr[4];
#pragma unroll
    for (int i = 0; i < 4; ++i) af[i] = *(const short8*)&As[cur][wr * 64 + i * 16 + c][8 * g];
#pragma unroll
    for (int j = 0; j < 4; ++j) bfr[j] = *(const short8*)&Bs[cur][wc * 64 + j * 16 + c][8 * g];
#pragma unroll
    for (int i = 0; i < 4; ++i)
#pragma unroll
      for (int j = 0; j < 4; ++j)
        acc[i][j] = __builtin_amdgcn_mfma_f32_16x16x32_bf16(af[i], bfr[j], acc[i][j], 0, 0, 0);

    if (ks + 1 < 16) {
#pragma unroll
      for (int it = 0; it < 2; ++it) {
        *(short8*)&As[cur ^ 1][srow + 64 * it][sc8] = pa[it];
        *(short8*)&Bs[cur ^ 1][srow + 64 * it][sc8] = pb[it];
      }
      if (ks + 2 < 16) {
        const int kk = (ks + 2) * 32;
#pragma unroll
        for (int it = 0; it < 2; ++it) {
          pa[it] = *(const short8*)&attb[(size_t)(m0 + srow + 64 * it) * E_ + kk + sc8];
          pb[it] = *(const short8*)&fcwbf[(size_t)(n0 + srow + 64 * it) * E_ + kk + sc8];
        }
      }
    }
    __syncthreads();
  }

#pragma unroll
  for (int i = 0; i < 4; ++i)
#pragma unroll
    for (int jj = 0; jj < 4; ++jj) {
      int grow = m0 + wr * 64 + i * 16 + 4 * g + jj;
#pragma unroll
      for (int j = 0; j < 4; ++j) {
        int col = n0 + wc * 64 + j * 16 + c;
        out[(size_t)grow * E_ + col] = acc[i][j][jj] + fcb[col];
      }
    }
}

extern "C" void kernel_launch(void* const* d_in, const int* in_sizes, int n_in,
                              void* d_out, int out_size, void* d_ws, size_t ws_size,
                              hipStream_t stream) {
  const float* q   = (const float*)d_in[0];
  const float* k   = (const float*)d_in[1];
  const float* v   = (const float*)d_in[2];
  const float* cq  = (const float*)d_in[3];
  const float* ck  = (const float*)d_in[4];
  const void*  am  = d_in[5];
  const void*  alm = d_in[6];
  const float* Wq  = (const float*)d_in[7];
  const float* bq  = (const float*)d_in[8];
  const float* Wk  = (const float*)d_in[9];
  const float* bk  = (const float*)d_in[10];
  const float* Wv  = (const float*)d_in[11];
  const float* bv  = (const float*)d_in[12];
  const float* bsc = (const float*)d_in[13];
  const float* rm  = (const float*)d_in[14];
  const float* fcw = (const float*)d_in[15];
  const float* fcb = (const float*)d_in[16];
  float* out = (float*)d_out;

  char* ws = (char*)d_ws;
  ushort* attb = (ushort*)(ws);                              // 8 MiB (bf16)
  ushort* vtg  = (ushort*)(ws + 16ull * 1024 * 1024);        // 8 MiB
  ushort* qkv  = (ushort*)(ws + 24ull * 1024 * 1024);        // 24 MiB (qh,kh,vh)
  ushort* m2d  = (ushort*)(ws + 48ull * 1024 * 1024);        // 32 MiB (sign bit = attn-discard)
  ushort* wt   = (ushort*)(ws + 80ull * 1024 * 1024);        // 1.5 MiB
  ushort* fcwbf= (ushort*)(ws + 80ull * 1024 * 1024 + 1536 * 1024); // 0.5 MiB

  ushort* qh = qkv;
  ushort* kh = qkv + (size_t)(B_ * H_ * S_ * D_);
  ushort* vh = qkv + 2 * (size_t)(B_ * H_ * S_ * D_);

  convert_weights_kernel<<<dim3(512, 4), 256, 0, stream>>>(Wq, Wk, Wv, fcw, wt, fcwbf);
  phase1_kernel<<<768 + 2048, 256, 0, stream>>>(q, k, v, wt, bq, bk, bv, qkv,
                                                cq, ck, am, alm, m2d);
  transpose_v_kernel<<<dim3(S_ / 64, B_ * H_), 256, 0, stream>>>(vh, vtg);
  flash_kernel<<<512, 512, 0, stream>>>(qh, kh, vtg, m2d, bsc, rm, attb);
  final_gemm_kernel<<<256, 256, 0, stream>>>(attb, fcwbf, fcb, out);
}

// Round 22
// 146.364 us; speedup vs baseline: 1.0794x; 1.0434x over previous
//
#include <hip/hip_runtime.h>

typedef unsigned short ushort;
typedef unsigned char uchar;
typedef unsigned long long u64;
typedef __attribute__((ext_vector_type(8))) short short8;   // 8 bf16 in 4 VGPRs
typedef __attribute__((ext_vector_type(4))) float f32x4;
typedef __attribute__((ext_vector_type(4))) unsigned int uint4v;

#define B_ 4
#define S_ 2048
#define E_ 512
#define H_ 8
#define D_ 64
#define LDT 40   // padded LDS row stride (bf16) for GEMM tiles
#define LDF 68   // flash LDS row stride: 2-way bank aliasing only (free)

__device__ inline ushort f2bf(float f) {
  union { float f; unsigned int u; } v; v.f = f;
  unsigned int u = v.u;
  unsigned int r = u + 0x7FFFu + ((u >> 16) & 1u);   // RNE
  return (ushort)(r >> 16);
}

// packed f32x2 -> bf16x2 (gfx950 v_cvt_pk_bf16_f32)
__device__ inline unsigned int cvt_pk_bf16(float a, float b) {
  unsigned int r;
  asm("v_cvt_pk_bf16_f32 %0, %1, %2" : "=v"(r) : "v"(a), "v"(b));
  return r;
}

// hazard-safe 2^x: compiler-visible intrinsic (TRANS hazards handled by backend)
__device__ inline float exp2_fast(float x) {
#if defined(__has_builtin)
#if __has_builtin(__builtin_amdgcn_exp2f)
  return __builtin_amdgcn_exp2f(x);
#else
  return __expf(x * 0.69314718056f);
#endif
#else
  return __expf(x * 0.69314718056f);
#endif
}

// zero out P lanes whose paired A2 value has the attn-discard sign bit set
__device__ inline short8 mask_keep(short8 p, short8 a2) {
  union U { short8 s; uint4v u; } P, A;
  P.s = p; A.s = a2;
#pragma unroll
  for (int i = 0; i < 4; ++i) {
    unsigned int t = A.u[i] & 0x80008000u;
    unsigned int dm = (t >> 15) * 0xFFFFu;   // 0xFFFF per discarded u16
    P.u[i] &= ~dm;
  }
  return P.s;
}

// 16-lane (DPP row) sum reduction on the VALU pipe (used once, post-loop)
__device__ inline float dpp_sum16(float v) {
  union { float f; int i; } s, t;
  s.f = v;
  t.i = __builtin_amdgcn_update_dpp(0, s.i, 0x128, 0xf, 0xf, false); s.f += t.f;
  t.i = __builtin_amdgcn_update_dpp(0, s.i, 0x124, 0xf, 0xf, false); s.f += t.f;
  t.i = __builtin_amdgcn_update_dpp(0, s.i, 0x122, 0xf, 0xf, false); s.f += t.f;
  t.i = __builtin_amdgcn_update_dpp(0, s.i, 0x121, 0xf, 0xf, false); s.f += t.f;
  return s.f;
}

// ---------------- convert weights: W[h][e][d]->wt[p][n][e] (y<3) and fcw->fcwbf (y==3) ----------------
__global__ __launch_bounds__(256) void convert_weights_kernel(
    const float* __restrict__ Wq, const float* __restrict__ Wk, const float* __restrict__ Wv,
    const float* __restrict__ fcw,
    ushort* __restrict__ wt, ushort* __restrict__ fcwbf) {
  const int p = blockIdx.y;
  const int n = blockIdx.x;
  if (p == 3) {
    const float* src = fcw + (size_t)n * E_;
    ushort* o = fcwbf + (size_t)n * E_;
    for (int e = threadIdx.x; e < E_; e += 256) o[e] = f2bf(src[e]);
    return;
  }
  const float* W = (p == 0) ? Wq : (p == 1) ? Wk : Wv;
  const int h = n >> 6, d = n & 63;
  ushort* o = wt + ((size_t)p * E_ + n) * E_;
  for (int e = threadIdx.x; e < E_; e += 256)
    o[e] = f2bf(W[((size_t)h * E_ + e) * D_ + d]);
}

// ---------------- PHASE 1 (fused): proj GEMM (0..767, V output written TRANSPOSED) + m2dist (768..2815)
// proj: single-buffered LDS + reg prefetch + chunked XCD swizzle; q pre-scaled 0.125*log2e.
// p==2 (V) epilogue transposes in LDS and writes vtg[bh][d][s] directly (deletes transpose_v kernel).
// m2dist: zero-LDS pure-wave ballot detect, 4 q-rows/block, batched ILP.
__global__ __launch_bounds__(256) void phase1_kernel(
    const float* __restrict__ qx, const float* __restrict__ kx, const float* __restrict__ vx,
    const ushort* __restrict__ wt,
    const float* __restrict__ bq, const float* __restrict__ bk, const float* __restrict__ bv,
    ushort* __restrict__ qkv, ushort* __restrict__ vtg,
    const float* __restrict__ cq, const float* __restrict__ ck,
    const void* __restrict__ am_raw, const void* __restrict__ alm_raw,
    ushort* __restrict__ m2d) {
  __shared__ ushort As[128][LDT], Bs[128][LDT];   // 20,480 B
  __shared__ ushort T[128][66];                   // 16,896 B (V-transpose staging)
  const int bid = blockIdx.x;
  const int tid = threadIdx.x;

  if (bid < 768) {
    // ================= proj GEMM: single-buffered LDS + register prefetch =================
    const int logical = (bid & 7) * 96 + (bid >> 3);
    const int p = logical >> 8;
    const int rem = logical & 255;
    const int m0 = (rem >> 2) * 128, n0 = (rem & 3) * 128;

    const float* A   = (p == 0) ? qx : (p == 1) ? kx : vx;
    const ushort* Bt = wt + (size_t)p * (E_ * E_);
    const float* bias = (p == 0) ? bq : (p == 1) ? bk : bv;
    const float osc = (p == 0) ? 0.125f * 1.44269504f : 1.0f;

    const int w = tid >> 6, lane = tid & 63;
    const int g = lane >> 4, c = lane & 15;
    const int wr = w >> 1, wc = w & 1;

    f32x4 acc[4][4];
#pragma unroll
    for (int i = 0; i < 4; ++i)
#pragma unroll
      for (int j = 0; j < 4; ++j) acc[i][j] = (f32x4){0, 0, 0, 0};

    const int srow = tid >> 2, sc8 = (tid & 3) * 8;
    float4 pa0[2], pa1[2];
    short8 pb[2];
#pragma unroll
    for (int it = 0; it < 2; ++it) {
      const float* ap = &A[(size_t)(m0 + srow + 64 * it) * E_ + sc8];
      pa0[it] = *(const float4*)ap;
      pa1[it] = *(const float4*)(ap + 4);
      pb[it] = *(const short8*)&Bt[(size_t)(n0 + srow + 64 * it) * E_ + sc8];
    }

    for (int kk = 0; kk < E_; kk += 32) {
      __syncthreads();
#pragma unroll
      for (int it = 0; it < 2; ++it) {
        unsigned int r0 = cvt_pk_bf16(pa0[it].x, pa0[it].y), r1 = cvt_pk_bf16(pa0[it].z, pa0[it].w);
        unsigned int r2 = cvt_pk_bf16(pa1[it].x, pa1[it].y), r3 = cvt_pk_bf16(pa1[it].z, pa1[it].w);
        short8 av;
        av[0] = (short)(ushort)r0; av[1] = (short)(ushort)(r0 >> 16);
        av[2] = (short)(ushort)r1; av[3] = (short)(ushort)(r1 >> 16);
        av[4] = (short)(ushort)r2; av[5] = (short)(ushort)(r2 >> 16);
        av[6] = (short)(ushort)r3; av[7] = (short)(ushort)(r3 >> 16);
        *(short8*)&As[srow + 64 * it][sc8] = av;
        *(short8*)&Bs[srow + 64 * it][sc8] = pb[it];
      }
      __syncthreads();
      if (kk + 32 < E_) {
#pragma unroll
        for (int it = 0; it < 2; ++it) {
          const float* ap = &A[(size_t)(m0 + srow + 64 * it) * E_ + kk + 32 + sc8];
          pa0[it] = *(const float4*)ap;
          pa1[it] = *(const float4*)(ap + 4);
          pb[it] = *(const short8*)&Bt[(size_t)(n0 + srow + 64 * it) * E_ + kk + 32 + sc8];
        }
      }
      short8 af[4], bfr[4];
#pragma unroll
      for (int i = 0; i < 4; ++i) af[i] = *(const short8*)&As[wr * 64 + i * 16 + c][8 * g];
#pragma unroll
      for (int j = 0; j < 4; ++j) bfr[j] = *(const short8*)&Bs[wc * 64 + j * 16 + c][8 * g];
#pragma unroll
      for (int i = 0; i < 4; ++i)
#pragma unroll
        for (int j = 0; j < 4; ++j)
          acc[i][j] = __builtin_amdgcn_mfma_f32_16x16x32_bf16(af[i], bfr[j], acc[i][j], 0, 0, 0);
    }

    if (p != 2) {
      // q/k heads: standard [bh][s][d] layout
      ushort* out = qkv + (size_t)p * (B_ * H_ * S_ * D_);
#pragma unroll
      for (int i = 0; i < 4; ++i)
#pragma unroll
        for (int jj = 0; jj < 4; ++jj) {
          int grow = m0 + wr * 64 + i * 16 + 4 * g + jj;
          int b = grow >> 11, s = grow & 2047;
#pragma unroll
          for (int j = 0; j < 4; ++j) {
            int col = n0 + wc * 64 + j * 16 + c;
            int h = col >> 6, d = col & 63;
            out[(((size_t)(b * H_ + h)) * S_ + s) * D_ + d] = f2bf((acc[i][j][jj] + bias[col]) * osc);
          }
        }
    } else {
      // V head: write TRANSPOSED vtg[bh][d][s] via 2-pass LDS staging (b,s0 are block constants)
      const int b = m0 >> 11, s0 = m0 & 2047;
#pragma unroll
      for (int pass = 0; pass < 2; ++pass) {
        __syncthreads();
        if (wr == pass) {
#pragma unroll
          for (int i = 0; i < 4; ++i)
#pragma unroll
            for (int jj = 0; jj < 4; ++jj) {
              int row_local = i * 16 + 4 * g + jj;   // 0..63
#pragma unroll
              for (int j = 0; j < 4; ++j) {
                int col = wc * 64 + j * 16 + c;       // 0..127
                T[col][row_local] = f2bf(acc[i][j][jj] + bias[n0 + col]);
              }
            }
        }
        __syncthreads();
        // 256 threads stream out: col = tid>>1, rows half = (tid&1)*32 .. +32 (contiguous in s)
        {
          const int col = tid >> 1;
          const int half = tid & 1;
          const int ngl = n0 + col;
          ushort* dst = vtg + (((size_t)(b * H_ + (ngl >> 6))) * D_ + (ngl & 63)) * S_
                        + s0 + pass * 64 + half * 32;
          const ushort* src = &T[col][half * 32];
#pragma unroll
          for (int v8 = 0; v8 < 4; ++v8)
            *(short8*)(dst + 8 * v8) = *(const short8*)(src + 8 * v8);
        }
      }
    }
    return;
  }

  // ================= m2dist: zero-LDS, 4 q-rows/block, batched ILP =================
  unsigned int probe = ((const unsigned int*)am_raw)[tid];   // L2-hot broadcast
  const bool isInt = !__any((probe & 0xFFFFFF00u) != 0);     // per-wave verdict, globally consistent

  const int mid = bid - 768;            // 0..2047
  const int b = mid >> 9;               // 512 blocks per batch
  const int q0 = (mid & 511) * 4;       // 4 consecutive q-rows
  const int k0 = tid * 8;
  const size_t rb0 = ((size_t)b * S_ + q0) * S_ + k0;

  float c24[24];
  {
    const float* ckp = ck + ((size_t)b * S_ + k0) * 3;
#pragma unroll
    for (int t = 0; t < 6; ++t) {
      float4 cv = *(const float4*)(ckp + 4 * t);
      c24[4 * t] = cv.x; c24[4 * t + 1] = cv.y; c24[4 * t + 2] = cv.z; c24[4 * t + 3] = cv.w;
    }
  }
  float qc[12];
  {
    const float* cqp = cq + ((size_t)b * S_ + q0) * 3;
#pragma unroll
    for (int t = 0; t < 3; ++t) {
      float4 cv = *(const float4*)(cqp + 4 * t);
      qc[4 * t] = cv.x; qc[4 * t + 1] = cv.y; qc[4 * t + 2] = cv.z; qc[4 * t + 3] = cv.w;
    }
  }
  u64 ab[4], lb[4];
  if (isInt) {
#pragma unroll
    for (int r = 0; r < 4; ++r) {
      const size_t rowbase = rb0 + (size_t)r * S_;
      int4 A0 = *(const int4*)&((const int*)am_raw)[rowbase];
      int4 A1 = *(const int4*)&((const int*)am_raw)[rowbase + 4];
      int4 L0 = *(const int4*)&((const int*)alm_raw)[rowbase];
      int4 L1 = *(const int4*)&((const int*)alm_raw)[rowbase + 4];
      u64 av = 0, lv = 0;
      av |= (u64)(A0.x ? 1 : 0);       lv |= (u64)(L0.x ? 1 : 0);
      av |= (u64)(A0.y ? 1 : 0) << 8;  lv |= (u64)(L0.y ? 1 : 0) << 8;
      av |= (u64)(A0.z ? 1 : 0) << 16; lv |= (u64)(L0.z ? 1 : 0) << 16;
      av |= (u64)(A0.w ? 1 : 0) << 24; lv |= (u64)(L0.w ? 1 : 0) << 24;
      av |= (u64)(A1.x ? 1 : 0) << 32; lv |= (u64)(L1.x ? 1 : 0) << 32;
      av |= (u64)(A1.y ? 1 : 0) << 40; lv |= (u64)(L1.y ? 1 : 0) << 40;
      av |= (u64)(A1.z ? 1 : 0) << 48; lv |= (u64)(L1.z ? 1 : 0) << 48;
      av |= (u64)(A1.w ? 1 : 0) << 56; lv |= (u64)(L1.w ? 1 : 0) << 56;
      ab[r] = av; lb[r] = lv;
    }
  } else {
#pragma unroll
    for (int r = 0; r < 4; ++r) {
      const size_t rowbase = rb0 + (size_t)r * S_;
      ab[r] = *(const u64*)&((const uchar*)am_raw)[rowbase];
      lb[r] = *(const u64*)&((const uchar*)alm_raw)[rowbase];
    }
  }

#pragma unroll
  for (int r = 0; r < 4; ++r) {
    const float qx2 = qc[3 * r], qy2 = qc[3 * r + 1], qz2 = qc[3 * r + 2];
    float dist[8];
#pragma unroll
    for (int j = 0; j < 8; ++j) {
      const float dx = qx2 - c24[3 * j], dy = qy2 - c24[3 * j + 1], dz = qz2 - c24[3 * j + 2];
      dist[j] = sqrtf(dx * dx + dy * dy + dz * dz);
    }
    short8 md;
#pragma unroll
    for (int jp = 0; jp < 4; ++jp) {
      const int a0 = (int)((ab[r] >> (16 * jp)) & 0xFF);
      const int a1 = (int)((ab[r] >> (16 * jp + 8)) & 0xFF);
      const int l0 = (int)((lb[r] >> (16 * jp)) & 0xFF);
      const int l1 = (int)((lb[r] >> (16 * jp + 8)) & 0xFF);
      unsigned int rr = cvt_pk_bf16(dist[2 * jp], dist[2 * jp + 1]);
      ushort v0 = (!a0 && !l0) ? (ushort)rr         : (ushort)0;
      ushort v1 = (!a1 && !l1) ? (ushort)(rr >> 16) : (ushort)0;
      if (a0) v0 |= 0x8000u;
      if (a1) v1 |= 0x8000u;
      md[2 * jp] = (short)v0; md[2 * jp + 1] = (short)v1;
    }
    *(short8*)&m2d[rb0 + (size_t)r * S_] = md;
  }
}

// ---------------- flash attention (r13-proven): QBLK=128, 8 waves, dbuf K/V, 1 barrier/tile ----------------
__global__ __launch_bounds__(512) void flash_kernel(
    const ushort* __restrict__ qh, const ushort* __restrict__ kh, const ushort* __restrict__ vtg,
    const ushort* __restrict__ m2d,
    const float* __restrict__ bscale, const float* __restrict__ rmean,
    ushort* __restrict__ attb) {
  const int flat = blockIdx.x;
  const int h = flat >> 6;
  const int grp = flat & 63;
  const int b = grp >> 4;
  const int qb = (grp & 15) * 128;
  const int bh = b * 8 + h;
  const int tid = threadIdx.x;
  const int w = tid >> 6, lane = tid & 63;
  const int g = lane >> 4, c = lane & 15;

  __shared__ ushort Kt[2][64][LDF];
  __shared__ ushort Vt[2][64][LDF];
  __shared__ ushort Pl[8][16][LDF];

  const size_t bhS = (size_t)bh * S_;
  const int qrow_a = qb + 16 * w + c;
  const short8 aq0 = *(const short8*)(qh + (bhS + qrow_a) * D_ + 8 * g);
  const short8 aq1 = *(const short8*)(qh + (bhS + qrow_a) * D_ + 8 * g + 32);

  const int skr = tid >> 3, sc8 = (tid & 7) * 8;
  const ushort* pk0 = kh + (bhS + skr) * D_ + sc8;
  const ushort* pv0 = vtg + ((size_t)bh * D_ + skr) * S_ + sc8;
  const ushort* pm0 = m2d + ((size_t)b * S_ + qrow_a) * S_ + 8 * g;
  const ushort* pm1 = pm0 + 32;

  f32x4 acc1[4], acc2[4];
#pragma unroll
  for (int t = 0; t < 4; ++t) { acc1[t] = (f32x4){0,0,0,0}; acc2[t] = (f32x4){0,0,0,0}; }
  float l[4] = {0, 0, 0, 0};

  {
    short8 k0 = *(const short8*)pk0;  pk0 += 64 * D_;
    short8 v0 = *(const short8*)pv0;  pv0 += 64;
    *(short8*)&Kt[0][skr][sc8] = k0;
    *(short8*)&Vt[0][skr][sc8] = v0;
  }
  short8 a2n0 = *(const short8*)pm0; pm0 += 64;
  short8 a2n1 = *(const short8*)pm1; pm1 += 64;
  short8 skn = *(const short8*)pk0;  pk0 += 64 * D_;
  short8 svn = *(const short8*)pv0;  pv0 += 64;
  __syncthreads();

  for (int kb = 0; kb < S_; kb += 64) {
    const int cur = (kb >> 6) & 1;
    short8 a2c0 = a2n0, a2c1 = a2n1;
    a2n0 = *(const short8*)pm0; pm0 += 64;
    a2n1 = *(const short8*)pm1; pm1 += 64;

    f32x4 sf[4];
    __builtin_amdgcn_s_setprio(1);
#pragma unroll
    for (int t = 0; t < 4; ++t) {
      short8 b0 = *(const short8*)&Kt[cur][16 * t + c][8 * g];
      short8 b1 = *(const short8*)&Kt[cur][16 * t + c][8 * g + 32];
      f32x4 z = (f32x4){0, 0, 0, 0};
      z = __builtin_amdgcn_mfma_f32_16x16x32_bf16(aq0, b0, z, 0, 0, 0);
      z = __builtin_amdgcn_mfma_f32_16x16x32_bf16(aq1, b1, z, 0, 0, 0);
      sf[t] = z;
    }
    __builtin_amdgcn_s_setprio(0);

#pragma unroll
    for (int t = 0; t < 4; ++t)
#pragma unroll
      for (int jp = 0; jp < 2; ++jp) {
        float p0 = exp2_fast(sf[t][2 * jp]);
        float p1 = exp2_fast(sf[t][2 * jp + 1]);
        l[2 * jp] += p0; l[2 * jp + 1] += p1;
        unsigned int r = cvt_pk_bf16(p0, p1);
        Pl[w][4 * g + 2 * jp][16 * t + c]     = (ushort)r;
        Pl[w][4 * g + 2 * jp + 1][16 * t + c] = (ushort)(r >> 16);
      }

    asm volatile("s_waitcnt lgkmcnt(0)" ::: "memory");
    __builtin_amdgcn_sched_barrier(0);

    short8 pa0 = *(const short8*)&Pl[w][c][8 * g];
    short8 pa1 = *(const short8*)&Pl[w][c][8 * g + 32];
    pa0 = mask_keep(pa0, a2c0);
    pa1 = mask_keep(pa1, a2c1);
    __builtin_amdgcn_s_setprio(1);
#pragma unroll
    for (int t2 = 0; t2 < 4; ++t2) {
      short8 v0 = *(const short8*)&Vt[cur][16 * t2 + c][8 * g];
      short8 v1 = *(const short8*)&Vt[cur][16 * t2 + c][8 * g + 32];
      acc1[t2] = __builtin_amdgcn_mfma_f32_16x16x32_bf16(pa0, v0, acc1[t2], 0, 0, 0);
      acc1[t2] = __builtin_amdgcn_mfma_f32_16x16x32_bf16(pa1, v1, acc1[t2], 0, 0, 0);
      acc2[t2] = __builtin_amdgcn_mfma_f32_16x16x32_bf16(a2c0, v0, acc2[t2], 0, 0, 0);
      acc2[t2] = __builtin_amdgcn_mfma_f32_16x16x32_bf16(a2c1, v1, acc2[t2], 0, 0, 0);
    }
    __builtin_amdgcn_s_setprio(0);

    if (kb + 64 < S_) {
      *(short8*)&Kt[cur ^ 1][skr][sc8] = skn;
      *(short8*)&Vt[cur ^ 1][skr][sc8] = svn;
      skn = *(const short8*)pk0;  pk0 += 64 * D_;
      svn = *(const short8*)pv0;  pv0 += 64;
    }
    __syncthreads();
  }

  float linv[4];
#pragma unroll
  for (int j = 0; j < 4; ++j) linv[j] = 1.0f / dpp_sum16(l[j]);
  const float scale = bscale[h] / rmean[h];
#pragma unroll
  for (int t2 = 0; t2 < 4; ++t2)
#pragma unroll
    for (int j = 0; j < 4; ++j) {
      int qr = qb + 16 * w + 4 * g + j;
      int d = 16 * t2 + c;
      attb[(((size_t)b * S_ + qr) * H_ + h) * D_ + d] =
          f2bf(acc1[t2][j] * linv[j] - scale * acc2[t2][j]);
    }
}

// ---------------- MFMA output GEMM: dbuf LDS (1 barrier/K-step) + reg prefetch + XCD swizzle ----------------
__global__ __launch_bounds__(256) void final_gemm_kernel(
    const ushort* __restrict__ attb, const ushort* __restrict__ fcwbf,
    const float* __restrict__ fcb, float* __restrict__ out) {
  const int phys = blockIdx.x;
  const int logical = (phys & 7) * 32 + (phys >> 3);
  const int m0 = (logical >> 2) * 128, n0 = (logical & 3) * 128;
  const int tid = threadIdx.x;
  const int w = tid >> 6, lane = tid & 63;
  const int g = lane >> 4, c = lane & 15;
  const int wr = w >> 1, wc = w & 1;

  __shared__ ushort As[2][128][LDT], Bs[2][128][LDT];

  f32x4 acc[4][4];
#pragma unroll
  for (int i = 0; i < 4; ++i)
#pragma unroll
    for (int j = 0; j < 4; ++j) acc[i][j] = (f32x4){0, 0, 0, 0};

  const int srow = tid >> 2, sc8 = (tid & 3) * 8;
  short8 pa[2], pb[2];

#pragma unroll
  for (int it = 0; it < 2; ++it) {
    *(short8*)&As[0][srow + 64 * it][sc8] = *(const short8*)&attb[(size_t)(m0 + srow + 64 * it) * E_ + sc8];
    *(short8*)&Bs[0][srow + 64 * it][sc8] = *(const short8*)&fcwbf[(size_t)(n0 + srow + 64 * it) * E_ + sc8];
  }
#pragma unroll
  for (int it = 0; it < 2; ++it) {
    pa[it] = *(const short8*)&attb[(size_t)(m0 + srow + 64 * it) * E_ + 32 + sc8];
    pb[it] = *(const short8*)&fcwbf[(size_t)(n0 + srow + 64 * it) * E_ + 32 + sc8];
  }
  __syncthreads();

  for (int ks = 0; ks < 16; ++ks) {
    const int cur = ks & 1;
    short8 af[4], bfr[4];
#pragma unroll
    for (int i = 0; i < 4; ++i) af[i] = *(const short8*)&As[cur][wr * 64 + i * 16 + c][8 * g];
#pragma unroll
    for (int j = 0; j < 4; ++j) bfr[j] = *(const short8*)&Bs[cur][wc * 64 + j * 16 + c][8 * g];
#pragma unroll
    for (int i = 0; i < 4; ++i)
#pragma unroll
      for (int j = 0; j < 4; ++j)
        acc[i][j] = __builtin_amdgcn_mfma_f32_16x16x32_bf16(af[i], bfr[j], acc[i][j], 0, 0, 0);

    if (ks + 1 < 16) {
#pragma unroll
      for (int it = 0; it < 2; ++it) {
        *(short8*)&As[cur ^ 1][srow + 64 * it][sc8] = pa[it];
        *(short8*)&Bs[cur ^ 1][srow + 64 * it][sc8] = pb[it];
      }
      if (ks + 2 < 16) {
        const int kk = (ks + 2) * 32;
#pragma unroll
        for (int it = 0; it < 2; ++it) {
          pa[it] = *(const short8*)&attb[(size_t)(m0 + srow + 64 * it) * E_ + kk + sc8];
          pb[it] = *(const short8*)&fcwbf[(size_t)(n0 + srow + 64 * it) * E_ + kk + sc8];
        }
      }
    }
    __syncthreads();
  }

#pragma unroll
  for (int i = 0; i < 4; ++i)
#pragma unroll
    for (int jj = 0; jj < 4; ++jj) {
      int grow = m0 + wr * 64 + i * 16 + 4 * g + jj;
#pragma unroll
      for (int j = 0; j < 4; ++j) {
        int col = n0 + wc * 64 + j * 16 + c;
        out[(size_t)grow * E_ + col] = acc[i][j][jj] + fcb[col];
      }
    }
}

extern "C" void kernel_launch(void* const* d_in, const int* in_sizes, int n_in,
                              void* d_out, int out_size, void* d_ws, size_t ws_size,
                              hipStream_t stream) {
  const float* q   = (const float*)d_in[0];
  const float* k   = (const float*)d_in[1];
  const float* v   = (const float*)d_in[2];
  const float* cq  = (const float*)d_in[3];
  const float* ck  = (const float*)d_in[4];
  const void*  am  = d_in[5];
  const void*  alm = d_in[6];
  const float* Wq  = (const float*)d_in[7];
  const float* bq  = (const float*)d_in[8];
  const float* Wk  = (const float*)d_in[9];
  const float* bk  = (const float*)d_in[10];
  const float* Wv  = (const float*)d_in[11];
  const float* bv  = (const float*)d_in[12];
  const float* bsc = (const float*)d_in[13];
  const float* rm  = (const float*)d_in[14];
  const float* fcw = (const float*)d_in[15];
  const float* fcb = (const float*)d_in[16];
  float* out = (float*)d_out;

  char* ws = (char*)d_ws;
  ushort* attb = (ushort*)(ws);                              // 8 MiB (bf16)
  ushort* vtg  = (ushort*)(ws + 16ull * 1024 * 1024);        // 8 MiB  [bh][d][s]
  ushort* qkv  = (ushort*)(ws + 24ull * 1024 * 1024);        // 16 MiB (qh,kh)
  ushort* m2d  = (ushort*)(ws + 48ull * 1024 * 1024);        // 32 MiB (sign bit = attn-discard)
  ushort* wt   = (ushort*)(ws + 80ull * 1024 * 1024);        // 1.5 MiB
  ushort* fcwbf= (ushort*)(ws + 80ull * 1024 * 1024 + 1536 * 1024); // 0.5 MiB

  ushort* qh = qkv;
  ushort* kh = qkv + (size_t)(B_ * H_ * S_ * D_);

  convert_weights_kernel<<<dim3(512, 4), 256, 0, stream>>>(Wq, Wk, Wv, fcw, wt, fcwbf);
  phase1_kernel<<<768 + 2048, 256, 0, stream>>>(q, k, v, wt, bq, bk, bv, qkv, vtg,
                                                cq, ck, am, alm, m2d);
  flash_kernel<<<512, 512, 0, stream>>>(qh, kh, vtg, m2d, bsc, rm, attb);
  final_gemm_kernel<<<256, 256, 0, stream>>>(attb, fcwbf, fcb, out);
}